// Round 1
// baseline (404.408 us; speedup 1.0000x reference)
//
#include <hip/hip_runtime.h>
#include <math.h>

#define NB 256      // batch
#define NS 512      // seq
#define ND 256      // hidden dim
#define NL 4        // layers
#define NITERS 10
#define BD (NB*ND)
#define DD (ND*ND)
#define KCH 32      // K chunk for GEMM staging
#define LDP 38      // padded LDS row stride (even for float2 align, conflict-light)

// ---------------------------------------------------------------------------
// Generic 32x32-tile GEMM body: C[m0..+32, n0..+32] = epi(sum_k fA(m,k)*fW(n,k))
// block = 256 threads, 2x2 outputs/thread, K = 256 in chunks of 32.
// ---------------------------------------------------------------------------
template <class FA, class FW, class FE>
__device__ __forceinline__ void gemm32(int m0, int n0, FA fA, FW fW, FE epi) {
    __shared__ float As[KCH * LDP];
    __shared__ float Ws[KCH * LDP];
    const int t = threadIdx.x;
    const int ty = t >> 4, tx = t & 15;         // 16x16 thread grid
    const int rowL = t >> 3, kq = (t & 7) << 2; // loader: 8 threads/row, 4 k each
    float acc00 = 0.f, acc01 = 0.f, acc10 = 0.f, acc11 = 0.f;
    for (int kc = 0; kc < ND; kc += KCH) {
#pragma unroll
        for (int i = 0; i < 4; ++i)
            As[(kq + i) * LDP + rowL] = fA(m0 + rowL, kc + kq + i);
#pragma unroll
        for (int i = 0; i < 4; ++i)
            Ws[(kq + i) * LDP + rowL] = fW(n0 + rowL, kc + kq + i);
        __syncthreads();
#pragma unroll
        for (int k = 0; k < KCH; ++k) {
            float a0 = As[k * LDP + 2 * ty], a1 = As[k * LDP + 2 * ty + 1];
            float w0 = Ws[k * LDP + 2 * tx], w1 = Ws[k * LDP + 2 * tx + 1];
            acc00 += a0 * w0; acc01 += a0 * w1;
            acc10 += a1 * w0; acc11 += a1 * w1;
        }
        __syncthreads();
    }
    epi(m0 + 2 * ty,     n0 + 2 * tx,     acc00);
    epi(m0 + 2 * ty,     n0 + 2 * tx + 1, acc01);
    epi(m0 + 2 * ty + 1, n0 + 2 * tx,     acc10);
    epi(m0 + 2 * ty + 1, n0 + 2 * tx + 1, acc11);
}

// ---------------------------------------------------------------------------
// K1: pooled[b,d] = mean_s( emb[ids[b,s],d] + pos[s,d] )
// grid = NB blocks, block = 1024 (4 s-groups x 256 d)
// ---------------------------------------------------------------------------
__global__ __launch_bounds__(1024) void k_pooled(const int* __restrict__ ids,
                                                 const float* __restrict__ emb,
                                                 const float* __restrict__ pos,
                                                 float* __restrict__ pooled) {
    const int b = blockIdx.x;
    const int t = threadIdx.x;
    const int d = t & 255, g = t >> 8; // g in 0..3
    __shared__ int sid[NS];
    __shared__ float part[3][ND];
    if (t < NS) sid[t] = ids[b * NS + t];
    __syncthreads();
    float acc = 0.f;
#pragma unroll 8
    for (int s = g; s < NS; s += 4)
        acc += emb[(size_t)sid[s] * ND + d] + pos[s * ND + d];
    if (g > 0) part[g - 1][d] = acc;
    __syncthreads();
    if (g == 0)
        pooled[b * ND + d] = (acc + part[0][d] + part[1][d] + part[2][d]) * (1.f / 512.f);
}

// ---------------------------------------------------------------------------
// init layer: out = tanh(in @ w^T + bias); optionally also store to out2 (ff)
// grid = 64 (8x8 tiles of 32x32)
// ---------------------------------------------------------------------------
__global__ __launch_bounds__(256) void k_init(const float* __restrict__ in,
                                              const float* __restrict__ w,
                                              const float* __restrict__ bias,
                                              float* __restrict__ out,
                                              float* __restrict__ out2) {
    const int tm = blockIdx.x >> 3, tn = blockIdx.x & 7;
    const int m0 = tm * 32, n0 = tn * 32;
    gemm32(m0, n0,
           [=](int m, int k) { return in[m * ND + k]; },
           [=](int n, int k) { return w[n * ND + k]; },
           [=](int m, int n, float acc) {
               float v = tanhf(acc + bias[n]);
               out[m * ND + n] = v;
               if (out2) out2[m * ND + n] = v;
           });
}

// ---------------------------------------------------------------------------
// predicts: pred[l] = reps[l] @ pred_w[l]^T + pred_b[l]   for all 4 layers
// grid = 256 (layer = bid>>6, tile = bid&63)
// ---------------------------------------------------------------------------
__global__ __launch_bounds__(256) void k_predict(const float* __restrict__ reps,
                                                 const float* __restrict__ pw,
                                                 const float* __restrict__ pb,
                                                 float* __restrict__ pred) {
    const int l = blockIdx.x >> 6;
    const int tile = blockIdx.x & 63;
    const int m0 = (tile >> 3) * 32, n0 = (tile & 7) * 32;
    const float* A = reps + l * BD;
    const float* W = pw + l * DD;
    const float* bias = pb + l * ND;
    float* out = pred + l * BD;
    gemm32(m0, n0,
           [=](int m, int k) { return A[m * ND + k]; },
           [=](int n, int k) { return W[n * ND + k]; },
           [=](int m, int n, float acc) { out[m * ND + n] = acc + bias[n]; });
}

// ---------------------------------------------------------------------------
// updates: te[l] = below - pred[l] + (l<3 ? 0.5*(reps[l]-pred[l+1]) : 0)
//          nreps[l] = reps[l] + 0.1*tanh(te[l] @ upd_w[l]^T + upd_b[l])
// grid = 256
// ---------------------------------------------------------------------------
__global__ __launch_bounds__(256) void k_update(const float* __restrict__ reps,
                                                const float* __restrict__ pred,
                                                const float* __restrict__ pooled,
                                                const float* __restrict__ uw,
                                                const float* __restrict__ ub,
                                                float* __restrict__ nreps) {
    const int l = blockIdx.x >> 6;
    const int tile = blockIdx.x & 63;
    const int m0 = (tile >> 3) * 32, n0 = (tile & 7) * 32;
    const float* below = (l == 0) ? pooled : reps + (l - 1) * BD;
    const float* prd = pred + l * BD;
    const float* prda = pred + (l + 1) * BD; // only deref'd if l<3
    const float* rep = reps + l * BD;
    const float* W = uw + l * DD;
    const float* bias = ub + l * ND;
    float* out = nreps + l * BD;
    const bool hasAbove = (l < 3);
    gemm32(m0, n0,
           [=](int m, int k) {
               int idx = m * ND + k;
               float te = below[idx] - prd[idx];
               if (hasAbove) te += 0.5f * (rep[idx] - prda[idx]);
               return te;
           },
           [=](int n, int k) { return W[n * ND + k]; },
           [=](int m, int n, float acc) {
               out[m * ND + n] = rep[m * ND + n] + 0.1f * tanhf(acc + bias[n]);
           });
}

// ---------------------------------------------------------------------------
// heads1: refined = reps3 + ff (written by start-half tn==0 blocks)
//         sq = refined @ sw^T + sb ; eq = refined @ ew^T + eb
// grid = 128 (half = bid>>6)
// ---------------------------------------------------------------------------
__global__ __launch_bounds__(256) void k_heads1(const float* __restrict__ reps3,
                                                const float* __restrict__ ff,
                                                const float* __restrict__ sw,
                                                const float* __restrict__ sb,
                                                const float* __restrict__ ew,
                                                const float* __restrict__ eb,
                                                float* __restrict__ sq,
                                                float* __restrict__ eq,
                                                float* __restrict__ refined) {
    const int half = blockIdx.x >> 6;
    const int tile = blockIdx.x & 63;
    const int m0 = (tile >> 3) * 32, n0 = (tile & 7) * 32;
    const float* W = half ? ew : sw;
    const float* bias = half ? eb : sb;
    float* out = half ? eq : sq;
    const bool wr = (half == 0) && (n0 == 0);
    gemm32(m0, n0,
           [=](int m, int k) {
               float v = reps3[m * ND + k] + ff[m * ND + k];
               if (wr) refined[m * ND + k] = v;
               return v;
           },
           [=](int n, int k) { return W[n * ND + k]; },
           [=](int m, int n, float acc) { out[m * ND + n] = acc + bias[n]; });
}

// ---------------------------------------------------------------------------
// heads2: sqk = sq @ key_w (non-transposed), eqk = eq @ key_w,
//         h = gelu(refined @ w1^T + b1), sqb/eqb = {sq,eq}·key_b
// grid = 161
// ---------------------------------------------------------------------------
__global__ __launch_bounds__(256) void k_heads2(const float* __restrict__ sq,
                                                const float* __restrict__ eq,
                                                const float* __restrict__ refined,
                                                const float* __restrict__ kw,
                                                const float* __restrict__ kb,
                                                const float* __restrict__ w1,
                                                const float* __restrict__ b1,
                                                float* __restrict__ sqk,
                                                float* __restrict__ eqk,
                                                float* __restrict__ sqb,
                                                float* __restrict__ eqb,
                                                float* __restrict__ h) {
    const int bid = blockIdx.x;
    if (bid == 160) { // per-row dots with key_b
        const int b = threadIdx.x;
        float a = 0.f, e = 0.f;
#pragma unroll 8
        for (int d0 = 0; d0 < ND; ++d0) {
            float kv = kb[d0];
            a += sq[b * ND + d0] * kv;
            e += eq[b * ND + d0] * kv;
        }
        sqb[b] = a;
        eqb[b] = e;
        return;
    }
    if (bid < 128) { // sqk / eqk: A @ key_w (key_w indexed [k][n])
        const int half = bid >> 6;
        const int tile = bid & 63;
        const int m0 = (tile >> 3) * 32, n0 = (tile & 7) * 32;
        const float* A = half ? eq : sq;
        float* out = half ? eqk : sqk;
        gemm32(m0, n0,
               [=](int m, int k) { return A[m * ND + k]; },
               [=](int n, int k) { return kw[k * ND + n]; },
               [=](int m, int n, float acc) { out[m * ND + n] = acc; });
        return;
    }
    { // h = gelu_exact(refined @ w1^T + b1), [256 x 128]
        const int tile = bid - 128;                 // 0..31
        const int m0 = (tile >> 2) * 32, n0 = (tile & 3) * 32;
        gemm32(m0, n0,
               [=](int m, int k) { return refined[m * ND + k]; },
               [=](int n, int k) { return w1[n * ND + k]; },
               [=](int m, int n, float acc) {
                   float x = acc + b1[n];
                   h[m * 128 + n] = 0.5f * x * (1.f + erff(x * 0.70710678118654752f));
               });
    }
}

// ---------------------------------------------------------------------------
// logits: out0[b,s] = (emb[ids[b,s]]+pos[s])·sqk[b] + sqb[b]
//         out1[b,s] = (emb[ids[b,s]]+pos[s])·eqk[b] + eqb[b]
//         block 256 -> answerable logits
// grid = 257, block = 512
// ---------------------------------------------------------------------------
__global__ __launch_bounds__(512) void k_logits(const int* __restrict__ ids,
                                                const float* __restrict__ emb,
                                                const float* __restrict__ pos,
                                                const float* __restrict__ sqk,
                                                const float* __restrict__ eqk,
                                                const float* __restrict__ sqb,
                                                const float* __restrict__ eqb,
                                                const float* __restrict__ h,
                                                const float* __restrict__ w2,
                                                const float* __restrict__ b2,
                                                float* __restrict__ out) {
    const int bid = blockIdx.x;
    const int t = threadIdx.x;
    if (bid == NB) { // answerable: out[2BS + 2b + j] = h[b]·w2[j] + b2[j]
        if (t < NB) {
            float a0 = b2[0], a1 = b2[1];
#pragma unroll 8
            for (int j = 0; j < 128; ++j) {
                float hv = h[t * 128 + j];
                a0 += hv * w2[j];
                a1 += hv * w2[128 + j];
            }
            out[2 * NB * NS + 2 * t] = a0;
            out[2 * NB * NS + 2 * t + 1] = a1;
        }
        return;
    }
    const int b = bid;
    __shared__ float sk[ND];
    __shared__ float ek[ND];
    __shared__ int sid[NS];
    if (t < ND) sk[t] = sqk[b * ND + t];
    else ek[t - ND] = eqk[b * ND + t - ND];
    sid[t] = ids[b * NS + t];
    if (t + 512 < NS) {} // NS==512, one element per thread
    __syncthreads();
    const int w = t >> 6, lane = t & 63;
    const float4 ks = *(const float4*)&sk[4 * lane];
    const float4 ke = *(const float4*)&ek[4 * lane];
    const float qbs = sqb[b], qbe = eqb[b];
    for (int s = w; s < NS; s += 8) {
        const int id = sid[s];
        const float4 e = *(const float4*)&emb[(size_t)id * ND + 4 * lane];
        const float4 p = *(const float4*)&pos[s * ND + 4 * lane];
        const float vx = e.x + p.x, vy = e.y + p.y, vz = e.z + p.z, vw = e.w + p.w;
        float ds = vx * ks.x + vy * ks.y + vz * ks.z + vw * ks.w;
        float de = vx * ke.x + vy * ke.y + vz * ke.z + vw * ke.w;
#pragma unroll
        for (int off = 32; off >= 1; off >>= 1) {
            ds += __shfl_xor(ds, off);
            de += __shfl_xor(de, off);
        }
        if (lane == 0) {
            out[b * NS + s] = ds + qbs;
            out[NB * NS + b * NS + s] = de + qbe;
        }
    }
}

// ---------------------------------------------------------------------------
extern "C" void kernel_launch(void* const* d_in, const int* in_sizes, int n_in,
                              void* d_out, int out_size, void* d_ws, size_t ws_size,
                              hipStream_t stream) {
    const int*   ids    = (const int*)d_in[0];
    const float* emb    = (const float*)d_in[1];
    const float* pos    = (const float*)d_in[2];
    const float* init_w = (const float*)d_in[3];
    const float* init_b = (const float*)d_in[4];
    const float* pred_w = (const float*)d_in[5];
    const float* pred_b = (const float*)d_in[6];
    const float* upd_w  = (const float*)d_in[7];
    const float* upd_b  = (const float*)d_in[8];
    const float* sw     = (const float*)d_in[9];
    const float* sb     = (const float*)d_in[10];
    const float* ew     = (const float*)d_in[11];
    const float* eb     = (const float*)d_in[12];
    const float* kw     = (const float*)d_in[13];
    const float* kb     = (const float*)d_in[14];
    const float* w1     = (const float*)d_in[15];
    const float* b1     = (const float*)d_in[16];
    const float* w2     = (const float*)d_in[17];
    const float* b2     = (const float*)d_in[18];
    float* out = (float*)d_out;

    float* ws = (float*)d_ws;
    float* pooled  = ws;
    float* repsA   = pooled + BD;
    float* repsB   = repsA + NL * BD;
    float* pred    = repsB + NL * BD;
    float* ff      = pred + NL * BD;
    float* refined = ff + BD;
    float* sq      = refined + BD;
    float* eq      = sq + BD;
    float* sqk     = eq + BD;
    float* eqk     = sqk + BD;
    float* sqb     = eqk + BD;
    float* eqb     = sqb + NB;
    float* h       = eqb + NB;

    k_pooled<<<NB, 1024, 0, stream>>>(ids, emb, pos, pooled);

    const float* cin = pooled;
    for (int l = 0; l < NL; ++l) {
        k_init<<<64, 256, 0, stream>>>(cin, init_w + l * DD, init_b + l * ND,
                                       repsA + l * BD, (l == NL - 1) ? ff : nullptr);
        cin = repsA + l * BD;
    }

    float* cur = repsA;
    float* nxt = repsB;
    for (int it = 0; it < NITERS; ++it) {
        k_predict<<<256, 256, 0, stream>>>(cur, pred_w, pred_b, pred);
        k_update<<<256, 256, 0, stream>>>(cur, pred, pooled, upd_w, upd_b, nxt);
        float* tmp = cur; cur = nxt; nxt = tmp;
    }

    k_heads1<<<128, 256, 0, stream>>>(cur + 3 * BD, ff, sw, sb, ew, eb, sq, eq, refined);
    k_heads2<<<161, 256, 0, stream>>>(sq, eq, refined, kw, kb, w1, b1,
                                      sqk, eqk, sqb, eqb, h);
    k_logits<<<NB + 1, 512, 0, stream>>>(ids, emb, pos, sqk, eqk, sqb, eqb,
                                         h, w2, b2, out);
}